// Round 1
// baseline (1792.437 us; speedup 1.0000x reference)
//
#include <hip/hip_runtime.h>

#define B_  4
#define C1  256   // Cin
#define C2  128   // Cout
#define HH  64
#define WW  64
#define H2  128
#define W2  128

// ---------------------------------------------------------------------------
// Kernel A: ConvTranspose2d(256->128, k=4, s=2, p=1) + bias
// y[b,o,oh,ow] = b1[o] + sum_{ci,kh,kw} x[b,ci,(oh+1-kh)/2,(ow+1-kw)/2] * w1[ci,o,kh,kw]
//   valid when (oh+1-kh) even & ih in [0,64), same for w.
// Block: 256 threads -> tile (co 0..127) x (ow0..ow0+31) for fixed (b, oh).
// Thread: 4 co x 4 ow register tile.
// ---------------------------------------------------------------------------
__global__ __launch_bounds__(256) void deconv_kernel(const float* __restrict__ x,
                                                     const float* __restrict__ w1,
                                                     const float* __restrict__ b1,
                                                     float* __restrict__ y) {
    const int ow0 = blockIdx.x * 32;
    const int oh  = blockIdx.y;
    const int b   = blockIdx.z;
    const int tid = threadIdx.x;
    const int wsub = tid & 7;    // 8 groups of 4 ow
    const int cog  = tid >> 3;   // 32 groups of 4 co
    const int co0  = cog * 4;

    const int p    = (oh + 1) & 1;          // kh parity
    const int ihA  = (oh + 1 - p) >> 1;     // ih for th=0 (kh=p); th=1 -> ihA-1
    const int iw_lo = (ow0 >> 1) - 1;

    __shared__ float w_lds[2 * 4 * 8 * 128]; // [th][kw][ci][co]  32 KB
    __shared__ float x_lds[8 * 2 * 18];      // [ci][th][iwi]

    float acc[4][4];
#pragma unroll
    for (int c = 0; c < 4; ++c)
#pragma unroll
        for (int u = 0; u < 4; ++u) acc[c][u] = 0.f;

    for (int chunk = 0; chunk < 32; ++chunk) {   // 256 ci / 8
        const int c0 = chunk * 8;
        // ---- stage weights: w_lds[((th*4+kw)*8 + ci)*128 + co]
        for (int idx = tid; idx < 8192; idx += 256) {
            const int co   = idx & 127;
            const int ci   = (idx >> 7) & 7;
            const int kwth = idx >> 10;       // 0..7
            const int kw   = kwth & 3;
            const int th   = kwth >> 2;
            w_lds[idx] = w1[(((c0 + ci) * C2 + co) * 4 + (p + 2 * th)) * 4 + kw];
        }
        // ---- stage x slab (zero-padded)
        for (int idx = tid; idx < 288; idx += 256) {
            const int iwi = idx % 18;
            const int r   = idx / 18;
            const int th  = r & 1;
            const int ci  = r >> 1;
            const int ih  = ihA - th;
            const int iw  = iw_lo + iwi;
            float v = 0.f;
            if (ih >= 0 && ih < HH && iw >= 0 && iw < WW)
                v = x[((b * C1 + c0 + ci) * HH + ih) * WW + iw];
            x_lds[(ci * 2 + th) * 18 + iwi] = v;
        }
        __syncthreads();

#pragma unroll
        for (int ci = 0; ci < 8; ++ci) {
            float xr[2][4];
#pragma unroll
            for (int th = 0; th < 2; ++th)
#pragma unroll
                for (int m = 0; m < 4; ++m)
                    xr[th][m] = x_lds[(ci * 2 + th) * 18 + wsub * 2 + m];
            float wr[4][2][4];
#pragma unroll
            for (int c = 0; c < 4; ++c)
#pragma unroll
                for (int th = 0; th < 2; ++th)
#pragma unroll
                    for (int kw = 0; kw < 4; ++kw)
                        wr[c][th][kw] = w_lds[((th * 4 + kw) * 8 + ci) * 128 + co0 + c];
#pragma unroll
            for (int u = 0; u < 4; ++u) {
#pragma unroll
                for (int tw = 0; tw < 2; ++tw) {
                    const int kw  = ((u + 1) & 1) + 2 * tw;
                    const int rel = ((u + 1 - kw) >> 1) + 1;  // x column within xr
#pragma unroll
                    for (int th = 0; th < 2; ++th) {
#pragma unroll
                        for (int c = 0; c < 4; ++c)
                            acc[c][u] += xr[th][rel] * wr[c][th][kw];
                    }
                }
            }
        }
        __syncthreads();
    }

#pragma unroll
    for (int c = 0; c < 4; ++c) {
        const float bias = b1[co0 + c];
        float4 v = make_float4(acc[c][0] + bias, acc[c][1] + bias,
                               acc[c][2] + bias, acc[c][3] + bias);
        float* dst = &y[((b * C2 + co0 + c) * H2 + oh) * W2 + ow0 + wsub * 4];
        *reinterpret_cast<float4*>(dst) = v;
    }
}

// ---------------------------------------------------------------------------
// Kernel B: pixel-adaptive 3x3 conv.
// out[b,o,h,w] = b2[o] + sum_{tap=(i,j)} k_tap[b,h,w] *
//                 sum_c w2[c,o,2-i,2-j] * y[b,c,h+i-1,w+j-1]
// k_tap = exp(-0.5 * sum_c (g_pad[b,c,h+i-1,w+j-1] - g[b,c,h,w])^2)
// Block: (o 0..127) x (w0..w0+31) tile for fixed (b,h). Thread: 4o x 4w.
// ---------------------------------------------------------------------------
__global__ __launch_bounds__(256) void pac_kernel(const float* __restrict__ y,
                                                  const float* __restrict__ guide,
                                                  const float* __restrict__ w2,
                                                  const float* __restrict__ b2,
                                                  float* __restrict__ out) {
    const int w0 = blockIdx.x * 32;
    const int h  = blockIdx.y;
    const int b  = blockIdx.z;
    const int tid  = threadIdx.x;
    const int wsub = tid & 7;
    const int og   = tid >> 3;
    const int o0   = og * 4;

    __shared__ float k_lds[9 * 32];
    __shared__ float w2_lds[8 * 9 * 128];   // [c][tap][o]  36 KB
    __shared__ float y_lds[8 * 3 * 34];     // [c][row][col]

    // ---- phase 1: adaptive kernel k for 9 taps x 32 pixels
    for (int t = tid; t < 288; t += 256) {
        const int tap = t >> 5;
        const int u   = t & 31;
        const int di  = tap / 3 - 1;
        const int dj  = tap % 3 - 1;
        const int hn  = h + di;
        const int wn  = w0 + u + dj;
        const float* gc = &guide[(size_t)b * C2 * H2 * W2 + h * W2 + w0 + u];
        float sum = 0.f;
        if (hn >= 0 && hn < H2 && wn >= 0 && wn < W2) {
            const float* gn = &guide[(size_t)b * C2 * H2 * W2 + hn * W2 + wn];
#pragma unroll 8
            for (int c = 0; c < C2; ++c) {
                const float d = gn[c * H2 * W2] - gc[c * H2 * W2];
                sum += d * d;
            }
        } else {
#pragma unroll 8
            for (int c = 0; c < C2; ++c) {
                const float d = gc[c * H2 * W2];
                sum += d * d;
            }
        }
        k_lds[t] = __expf(-0.5f * sum);
    }
    __syncthreads();

    float kreg[9][4];
#pragma unroll
    for (int tap = 0; tap < 9; ++tap)
#pragma unroll
        for (int u = 0; u < 4; ++u)
            kreg[tap][u] = k_lds[tap * 32 + wsub * 4 + u];

    float acc[4][4];
#pragma unroll
    for (int oc = 0; oc < 4; ++oc)
#pragma unroll
        for (int u = 0; u < 4; ++u) acc[oc][u] = 0.f;

    for (int chunk = 0; chunk < 16; ++chunk) {   // 128 c / 8
        const int c0 = chunk * 8;
        // ---- stage y rows h-1..h+1, cols w0-1..w0+32 (zero-padded)
        for (int idx = tid; idx < 816; idx += 256) {
            const int col = idx % 34;
            const int r   = (idx / 34) % 3;
            const int c   = idx / 102;
            const int hh  = h + r - 1;
            const int ww  = w0 - 1 + col;
            float v = 0.f;
            if (hh >= 0 && hh < H2 && ww >= 0 && ww < W2)
                v = y[((b * C2 + c0 + c) * H2 + hh) * W2 + ww];
            y_lds[idx] = v;
        }
        // ---- stage w2 as [c][tap][o] with flip applied
        for (int idx = tid; idx < 9216; idx += 256) {
            const int o   = idx & 127;
            const int tap = (idx >> 7) % 9;
            const int c   = idx / 1152;
            const int i   = tap / 3;
            const int j   = tap % 3;
            w2_lds[idx] = w2[(((c0 + c) * C2 + o) * 3 + (2 - i)) * 3 + (2 - j)];
        }
        __syncthreads();

#pragma unroll
        for (int c = 0; c < 8; ++c) {
            float s[9][4];
#pragma unroll
            for (int tap = 0; tap < 9; ++tap) {
                const int di = tap / 3;
                const int dj = tap % 3;
#pragma unroll
                for (int u = 0; u < 4; ++u) {
                    const float yv = y_lds[(c * 3 + di) * 34 + wsub * 4 + u + dj];
                    s[tap][u] = yv * kreg[tap][u];
                }
            }
#pragma unroll
            for (int oc = 0; oc < 4; ++oc) {
#pragma unroll
                for (int tap = 0; tap < 9; ++tap) {
                    const float wv = w2_lds[(c * 9 + tap) * 128 + o0 + oc];
#pragma unroll
                    for (int u = 0; u < 4; ++u)
                        acc[oc][u] += s[tap][u] * wv;
                }
            }
        }
        __syncthreads();
    }

#pragma unroll
    for (int oc = 0; oc < 4; ++oc) {
        const float bias = b2[o0 + oc];
        float4 v = make_float4(acc[oc][0] + bias, acc[oc][1] + bias,
                               acc[oc][2] + bias, acc[oc][3] + bias);
        float* dst = &out[((b * C2 + o0 + oc) * H2 + h) * W2 + w0 + wsub * 4];
        *reinterpret_cast<float4*>(dst) = v;
    }
}

extern "C" void kernel_launch(void* const* d_in, const int* in_sizes, int n_in,
                              void* d_out, int out_size, void* d_ws, size_t ws_size,
                              hipStream_t stream) {
    const float* x     = (const float*)d_in[0];
    const float* guide = (const float*)d_in[1];
    const float* w1    = (const float*)d_in[2];
    const float* b1    = (const float*)d_in[3];
    const float* w2    = (const float*)d_in[4];
    const float* b2    = (const float*)d_in[5];
    float* out = (float*)d_out;
    float* y   = (float*)d_ws;   // 4*128*128*128 fp32 = 33.5 MB intermediate

    dim3 block(256);
    dim3 grid(4, H2, B_);   // (w-tiles, rows, batch)
    deconv_kernel<<<grid, block, 0, stream>>>(x, w1, b1, y);
    pac_kernel<<<grid, block, 0, stream>>>(y, guide, w2, b2, out);
}

// Round 2
// 909.234 us; speedup vs baseline: 1.9714x; 1.9714x over previous
//
#include <hip/hip_runtime.h>

#define B_  4
#define C1  256   // Cin
#define C2  128   // Cout
#define HH  64
#define WW  64
#define H2  128
#define W2  128

// Workspace layout (bytes)
#define W1T_OFF   0u
#define W1T_ELEMS (4 * 4 * C1 * C2)              // [kh][kw][ci][co] = 524288
#define W2T_OFF   (W1T_ELEMS * 4)                // 2097152
#define W2T_ELEMS (C2 * 9 * C2)                  // [ci][tap][o] = 147456
#define Y_OFF     (W2T_OFF + W2T_ELEMS * 4)      // 2686976
#define Y_ELEMS   (B_ * C2 * H2 * W2)            // 8388608
#define WS_NEEDED ((size_t)Y_OFF + (size_t)Y_ELEMS * 4)

// ---------------------------------------------------------------------------
// Weight transposes (run once per launch; 2.6 MB total, negligible)
// ---------------------------------------------------------------------------
__global__ void w1_transpose_kernel(const float* __restrict__ w1, float* __restrict__ w1t) {
    int i = blockIdx.x * 256 + threadIdx.x;          // out index, coalesced write
    const int co = i & 127;
    const int ci = (i >> 7) & 255;
    const int kw = (i >> 15) & 3;
    const int kh = i >> 17;
    w1t[i] = w1[((ci * C2 + co) * 4 + kh) * 4 + kw];
}

__global__ void w2_transpose_kernel(const float* __restrict__ w2, float* __restrict__ w2t) {
    int i = blockIdx.x * 256 + threadIdx.x;          // out index = (ci*9+tap)*128+o
    if (i >= W2T_ELEMS) return;
    const int o   = i & 127;
    const int tap = (i >> 7) % 9;
    const int ci  = i / 1152;
    const int fi  = 2 - tap / 3;                     // flip baked in
    const int fj  = 2 - tap % 3;
    w2t[i] = w2[((ci * C2 + o) * 3 + fi) * 3 + fj];
}

// ---------------------------------------------------------------------------
// Kernel A: ConvTranspose2d(256->128, k=4, s=2, p=1) + bias.
// Block: (co 0..127) x (ow0..ow0+31) for fixed (b, oh). Thread: 4co x 4ow.
// Weights read from pre-transposed w1t[kh][kw][ci][co] -> coalesced staging.
// ---------------------------------------------------------------------------
__global__ __launch_bounds__(256) void deconv_kernel(const float* __restrict__ x,
                                                     const float* __restrict__ w1t,
                                                     const float* __restrict__ b1,
                                                     float* __restrict__ y) {
    const int ow0 = blockIdx.x * 32;
    const int oh  = blockIdx.y;
    const int b   = blockIdx.z;
    const int tid = threadIdx.x;
    const int wsub = tid & 7;
    const int cog  = tid >> 3;
    const int co0  = cog * 4;

    const int p    = (oh + 1) & 1;          // kh parity
    const int ihA  = (oh + 1 - p) >> 1;     // ih for th=0 (kh=p); th=1 -> ihA-1
    const int iw_lo = (ow0 >> 1) - 1;

    __shared__ float w_lds[2 * 4 * 8 * 128]; // [th][kw][ci][co]  32 KB
    __shared__ float x_lds[8 * 2 * 18];      // [ci][th][iwi]

    float acc[4][4];
#pragma unroll
    for (int c = 0; c < 4; ++c)
#pragma unroll
        for (int u = 0; u < 4; ++u) acc[c][u] = 0.f;

    for (int chunk = 0; chunk < 32; ++chunk) {   // 256 ci / 8
        const int c0 = chunk * 8;
        // ---- stage weights, coalesced float4: w_lds[((th*4+kw)*8+ci)*128+co]
#pragma unroll
        for (int it = 0; it < 8; ++it) {
            const int idx4 = it * 256 + tid;         // 0..2047
            const int co4  = idx4 & 31;
            const int ci   = (idx4 >> 5) & 7;
            const int kwth = idx4 >> 8;              // 0..7
            const int kw   = kwth & 3;
            const int th   = kwth >> 1 & 2 ? 0 : 0;  // placeholder (recomputed below)
            const int th2  = kwth >> 2;
            const float4 v = *reinterpret_cast<const float4*>(
                &w1t[((((p + 2 * th2) * 4 + kw) * C1 + (c0 + ci)) * C2) + co4 * 4]);
            reinterpret_cast<float4*>(w_lds)[idx4] = v;
            (void)th;
        }
        // ---- stage x slab (zero-padded)
        for (int idx = tid; idx < 288; idx += 256) {
            const int iwi = idx % 18;
            const int r   = idx / 18;
            const int th  = r & 1;
            const int ci  = r >> 1;
            const int ih  = ihA - th;
            const int iw  = iw_lo + iwi;
            float v = 0.f;
            if (ih >= 0 && ih < HH && iw >= 0 && iw < WW)
                v = x[((b * C1 + c0 + ci) * HH + ih) * WW + iw];
            x_lds[(ci * 2 + th) * 18 + iwi] = v;
        }
        __syncthreads();

#pragma unroll
        for (int ci = 0; ci < 8; ++ci) {
            float xr[2][4];
#pragma unroll
            for (int th = 0; th < 2; ++th)
#pragma unroll
                for (int m = 0; m < 4; ++m)
                    xr[th][m] = x_lds[(ci * 2 + th) * 18 + wsub * 2 + m];
            float wr[4][2][4];
#pragma unroll
            for (int c = 0; c < 4; ++c)
#pragma unroll
                for (int th = 0; th < 2; ++th)
#pragma unroll
                    for (int kw = 0; kw < 4; ++kw)
                        wr[c][th][kw] = w_lds[((th * 4 + kw) * 8 + ci) * 128 + co0 + c];
#pragma unroll
            for (int u = 0; u < 4; ++u) {
#pragma unroll
                for (int tw = 0; tw < 2; ++tw) {
                    const int kw  = ((u + 1) & 1) + 2 * tw;
                    const int rel = ((u + 1 - kw) >> 1) + 1;
#pragma unroll
                    for (int th = 0; th < 2; ++th) {
#pragma unroll
                        for (int c = 0; c < 4; ++c)
                            acc[c][u] += xr[th][rel] * wr[c][th][kw];
                    }
                }
            }
        }
        __syncthreads();
    }

#pragma unroll
    for (int c = 0; c < 4; ++c) {
        const float bias = b1[co0 + c];
        float4 v = make_float4(acc[c][0] + bias, acc[c][1] + bias,
                               acc[c][2] + bias, acc[c][3] + bias);
        float* dst = &y[((b * C2 + co0 + c) * H2 + oh) * W2 + ow0 + wsub * 4];
        *reinterpret_cast<float4*>(dst) = v;
    }
}

// ---------------------------------------------------------------------------
// Kernel B: pixel-adaptive 3x3 conv, weights from w2t[ci][tap][o] (pre-flipped).
// ---------------------------------------------------------------------------
__global__ __launch_bounds__(256) void pac_kernel(const float* __restrict__ y,
                                                  const float* __restrict__ guide,
                                                  const float* __restrict__ w2t,
                                                  const float* __restrict__ b2,
                                                  float* __restrict__ out) {
    const int w0 = blockIdx.x * 32;
    const int h  = blockIdx.y;
    const int b  = blockIdx.z;
    const int tid  = threadIdx.x;
    const int wsub = tid & 7;
    const int og   = tid >> 3;
    const int o0   = og * 4;

    __shared__ float k_lds[9 * 32];
    __shared__ float w2_lds[8 * 9 * 128];   // [c][tap][o]  36 KB
    __shared__ float y_lds[8 * 3 * 34];     // [c][row][col]

    // ---- phase 1: adaptive kernel k for 9 taps x 32 pixels
    for (int t = tid; t < 288; t += 256) {
        const int tap = t >> 5;
        const int u   = t & 31;
        const int di  = tap / 3 - 1;
        const int dj  = tap % 3 - 1;
        const int hn  = h + di;
        const int wn  = w0 + u + dj;
        const float* gc = &guide[(size_t)b * C2 * H2 * W2 + h * W2 + w0 + u];
        float sum = 0.f;
        if (hn >= 0 && hn < H2 && wn >= 0 && wn < W2) {
            const float* gn = &guide[(size_t)b * C2 * H2 * W2 + hn * W2 + wn];
#pragma unroll 8
            for (int c = 0; c < C2; ++c) {
                const float d = gn[c * H2 * W2] - gc[c * H2 * W2];
                sum += d * d;
            }
        } else {
#pragma unroll 8
            for (int c = 0; c < C2; ++c) {
                const float d = gc[c * H2 * W2];
                sum += d * d;
            }
        }
        k_lds[t] = __expf(-0.5f * sum);
    }
    __syncthreads();

    float kreg[9][4];
#pragma unroll
    for (int tap = 0; tap < 9; ++tap)
#pragma unroll
        for (int u = 0; u < 4; ++u)
            kreg[tap][u] = k_lds[tap * 32 + wsub * 4 + u];

    float acc[4][4];
#pragma unroll
    for (int oc = 0; oc < 4; ++oc)
#pragma unroll
        for (int u = 0; u < 4; ++u) acc[oc][u] = 0.f;

    for (int chunk = 0; chunk < 16; ++chunk) {   // 128 c / 8
        const int c0 = chunk * 8;
        // ---- stage y rows h-1..h+1, cols w0-1..w0+32 (zero-padded)
        for (int idx = tid; idx < 816; idx += 256) {
            const int col = idx % 34;
            const int r   = (idx / 34) % 3;
            const int c   = idx / 102;
            const int hh  = h + r - 1;
            const int ww  = w0 - 1 + col;
            float v = 0.f;
            if (hh >= 0 && hh < H2 && ww >= 0 && ww < W2)
                v = y[((b * C2 + c0 + c) * H2 + hh) * W2 + ww];
            y_lds[idx] = v;
        }
        // ---- stage w2 chunk: contiguous 9216 floats = 2304 float4 (coalesced)
        {
            const float4* src = reinterpret_cast<const float4*>(&w2t[c0 * 9 * C2]);
            float4* dst = reinterpret_cast<float4*>(w2_lds);
#pragma unroll
            for (int it = 0; it < 9; ++it)
                dst[it * 256 + tid] = src[it * 256 + tid];
        }
        __syncthreads();

#pragma unroll
        for (int c = 0; c < 8; ++c) {
            float s[9][4];
#pragma unroll
            for (int tap = 0; tap < 9; ++tap) {
                const int di = tap / 3;
                const int dj = tap % 3;
#pragma unroll
                for (int u = 0; u < 4; ++u) {
                    const float yv = y_lds[(c * 3 + di) * 34 + wsub * 4 + u + dj];
                    s[tap][u] = yv * kreg[tap][u];
                }
            }
#pragma unroll
            for (int oc = 0; oc < 4; ++oc) {
#pragma unroll
                for (int tap = 0; tap < 9; ++tap) {
                    const float wv = w2_lds[(c * 9 + tap) * 128 + o0 + oc];
#pragma unroll
                    for (int u = 0; u < 4; ++u)
                        acc[oc][u] += s[tap][u] * wv;
                }
            }
        }
        __syncthreads();
    }

#pragma unroll
    for (int oc = 0; oc < 4; ++oc) {
        const float bias = b2[o0 + oc];
        float4 v = make_float4(acc[oc][0] + bias, acc[oc][1] + bias,
                               acc[oc][2] + bias, acc[oc][3] + bias);
        float* dst = &out[((b * C2 + o0 + oc) * H2 + h) * W2 + w0 + wsub * 4];
        *reinterpret_cast<float4*>(dst) = v;
    }
}

// ---------------------------------------------------------------------------
// Fallback (round-1) kernels: used only if ws_size can't fit transposed weights.
// ---------------------------------------------------------------------------
__global__ __launch_bounds__(256) void deconv_kernel_fb(const float* __restrict__ x,
                                                        const float* __restrict__ w1,
                                                        const float* __restrict__ b1,
                                                        float* __restrict__ y) {
    const int ow0 = blockIdx.x * 32;
    const int oh  = blockIdx.y;
    const int b   = blockIdx.z;
    const int tid = threadIdx.x;
    const int wsub = tid & 7;
    const int cog  = tid >> 3;
    const int co0  = cog * 4;
    const int p    = (oh + 1) & 1;
    const int ihA  = (oh + 1 - p) >> 1;
    const int iw_lo = (ow0 >> 1) - 1;

    __shared__ float w_lds[2 * 4 * 8 * 128];
    __shared__ float x_lds[8 * 2 * 18];

    float acc[4][4];
#pragma unroll
    for (int c = 0; c < 4; ++c)
#pragma unroll
        for (int u = 0; u < 4; ++u) acc[c][u] = 0.f;

    for (int chunk = 0; chunk < 32; ++chunk) {
        const int c0 = chunk * 8;
        for (int idx = tid; idx < 8192; idx += 256) {
            const int co   = idx & 127;
            const int ci   = (idx >> 7) & 7;
            const int kwth = idx >> 10;
            const int kw   = kwth & 3;
            const int th   = kwth >> 2;
            w_lds[idx] = w1[(((c0 + ci) * C2 + co) * 4 + (p + 2 * th)) * 4 + kw];
        }
        for (int idx = tid; idx < 288; idx += 256) {
            const int iwi = idx % 18;
            const int r   = idx / 18;
            const int th  = r & 1;
            const int ci  = r >> 1;
            const int ih  = ihA - th;
            const int iw  = iw_lo + iwi;
            float v = 0.f;
            if (ih >= 0 && ih < HH && iw >= 0 && iw < WW)
                v = x[((b * C1 + c0 + ci) * HH + ih) * WW + iw];
            x_lds[(ci * 2 + th) * 18 + iwi] = v;
        }
        __syncthreads();
#pragma unroll
        for (int ci = 0; ci < 8; ++ci) {
            float xr[2][4];
#pragma unroll
            for (int th = 0; th < 2; ++th)
#pragma unroll
                for (int m = 0; m < 4; ++m)
                    xr[th][m] = x_lds[(ci * 2 + th) * 18 + wsub * 2 + m];
            float wr[4][2][4];
#pragma unroll
            for (int c = 0; c < 4; ++c)
#pragma unroll
                for (int th = 0; th < 2; ++th)
#pragma unroll
                    for (int kw = 0; kw < 4; ++kw)
                        wr[c][th][kw] = w_lds[((th * 4 + kw) * 8 + ci) * 128 + co0 + c];
#pragma unroll
            for (int u = 0; u < 4; ++u) {
#pragma unroll
                for (int tw = 0; tw < 2; ++tw) {
                    const int kw  = ((u + 1) & 1) + 2 * tw;
                    const int rel = ((u + 1 - kw) >> 1) + 1;
#pragma unroll
                    for (int th = 0; th < 2; ++th)
#pragma unroll
                        for (int c = 0; c < 4; ++c)
                            acc[c][u] += xr[th][rel] * wr[c][th][kw];
                }
            }
        }
        __syncthreads();
    }
#pragma unroll
    for (int c = 0; c < 4; ++c) {
        const float bias = b1[co0 + c];
        float4 v = make_float4(acc[c][0] + bias, acc[c][1] + bias,
                               acc[c][2] + bias, acc[c][3] + bias);
        float* dst = &y[((b * C2 + co0 + c) * H2 + oh) * W2 + ow0 + wsub * 4];
        *reinterpret_cast<float4*>(dst) = v;
    }
}

__global__ __launch_bounds__(256) void pac_kernel_fb(const float* __restrict__ y,
                                                     const float* __restrict__ guide,
                                                     const float* __restrict__ w2,
                                                     const float* __restrict__ b2,
                                                     float* __restrict__ out) {
    const int w0 = blockIdx.x * 32;
    const int h  = blockIdx.y;
    const int b  = blockIdx.z;
    const int tid  = threadIdx.x;
    const int wsub = tid & 7;
    const int og   = tid >> 3;
    const int o0   = og * 4;

    __shared__ float k_lds[9 * 32];
    __shared__ float w2_lds[8 * 9 * 128];
    __shared__ float y_lds[8 * 3 * 34];

    for (int t = tid; t < 288; t += 256) {
        const int tap = t >> 5;
        const int u   = t & 31;
        const int di  = tap / 3 - 1;
        const int dj  = tap % 3 - 1;
        const int hn  = h + di;
        const int wn  = w0 + u + dj;
        const float* gc = &guide[(size_t)b * C2 * H2 * W2 + h * W2 + w0 + u];
        float sum = 0.f;
        if (hn >= 0 && hn < H2 && wn >= 0 && wn < W2) {
            const float* gn = &guide[(size_t)b * C2 * H2 * W2 + hn * W2 + wn];
#pragma unroll 8
            for (int c = 0; c < C2; ++c) {
                const float d = gn[c * H2 * W2] - gc[c * H2 * W2];
                sum += d * d;
            }
        } else {
#pragma unroll 8
            for (int c = 0; c < C2; ++c) {
                const float d = gc[c * H2 * W2];
                sum += d * d;
            }
        }
        k_lds[t] = __expf(-0.5f * sum);
    }
    __syncthreads();

    float kreg[9][4];
#pragma unroll
    for (int tap = 0; tap < 9; ++tap)
#pragma unroll
        for (int u = 0; u < 4; ++u)
            kreg[tap][u] = k_lds[tap * 32 + wsub * 4 + u];

    float acc[4][4];
#pragma unroll
    for (int oc = 0; oc < 4; ++oc)
#pragma unroll
        for (int u = 0; u < 4; ++u) acc[oc][u] = 0.f;

    for (int chunk = 0; chunk < 16; ++chunk) {
        const int c0 = chunk * 8;
        for (int idx = tid; idx < 816; idx += 256) {
            const int col = idx % 34;
            const int r   = (idx / 34) % 3;
            const int c   = idx / 102;
            const int hh  = h + r - 1;
            const int ww  = w0 - 1 + col;
            float v = 0.f;
            if (hh >= 0 && hh < H2 && ww >= 0 && ww < W2)
                v = y[((b * C2 + c0 + c) * H2 + hh) * W2 + ww];
            y_lds[idx] = v;
        }
        for (int idx = tid; idx < 9216; idx += 256) {
            const int o   = idx & 127;
            const int tap = (idx >> 7) % 9;
            const int c   = idx / 1152;
            const int i   = tap / 3;
            const int j   = tap % 3;
            w2_lds[idx] = w2[(((c0 + c) * C2 + o) * 3 + (2 - i)) * 3 + (2 - j)];
        }
        __syncthreads();
#pragma unroll
        for (int c = 0; c < 8; ++c) {
            float s[9][4];
#pragma unroll
            for (int tap = 0; tap < 9; ++tap) {
                const int di = tap / 3;
                const int dj = tap % 3;
#pragma unroll
                for (int u = 0; u < 4; ++u) {
                    const float yv = y_lds[(c * 3 + di) * 34 + wsub * 4 + u + dj];
                    s[tap][u] = yv * kreg[tap][u];
                }
            }
#pragma unroll
            for (int oc = 0; oc < 4; ++oc) {
#pragma unroll
                for (int tap = 0; tap < 9; ++tap) {
                    const float wv = w2_lds[(c * 9 + tap) * 128 + o0 + oc];
#pragma unroll
                    for (int u = 0; u < 4; ++u)
                        acc[oc][u] += s[tap][u] * wv;
                }
            }
        }
        __syncthreads();
    }
#pragma unroll
    for (int oc = 0; oc < 4; ++oc) {
        const float bias = b2[o0 + oc];
        float4 v = make_float4(acc[oc][0] + bias, acc[oc][1] + bias,
                               acc[oc][2] + bias, acc[oc][3] + bias);
        float* dst = &out[((b * C2 + o0 + oc) * H2 + h) * W2 + w0 + wsub * 4];
        *reinterpret_cast<float4*>(dst) = v;
    }
}

extern "C" void kernel_launch(void* const* d_in, const int* in_sizes, int n_in,
                              void* d_out, int out_size, void* d_ws, size_t ws_size,
                              hipStream_t stream) {
    const float* x     = (const float*)d_in[0];
    const float* guide = (const float*)d_in[1];
    const float* w1    = (const float*)d_in[2];
    const float* b1    = (const float*)d_in[3];
    const float* w2    = (const float*)d_in[4];
    const float* b2    = (const float*)d_in[5];
    float* out = (float*)d_out;

    dim3 block(256);
    dim3 grid(4, H2, B_);

    if (ws_size >= WS_NEEDED) {
        float* w1t = (float*)((char*)d_ws + W1T_OFF);
        float* w2t = (float*)((char*)d_ws + W2T_OFF);
        float* y   = (float*)((char*)d_ws + Y_OFF);
        w1_transpose_kernel<<<W1T_ELEMS / 256, 256, 0, stream>>>(w1, w1t);
        w2_transpose_kernel<<<(W2T_ELEMS + 255) / 256, 256, 0, stream>>>(w2, w2t);
        deconv_kernel<<<grid, block, 0, stream>>>(x, w1t, b1, y);
        pac_kernel<<<grid, block, 0, stream>>>(y, guide, w2t, b2, out);
    } else {
        float* y = (float*)d_ws;
        deconv_kernel_fb<<<grid, block, 0, stream>>>(x, w1, b1, y);
        pac_kernel_fb<<<grid, block, 0, stream>>>(y, guide, w2, b2, out);
    }
}

// Round 3
// 419.392 us; speedup vs baseline: 4.2739x; 2.1680x over previous
//
#include <hip/hip_runtime.h>

#define B_  4
#define C1  256
#define C2  128
#define HH  64
#define WW  64
#define H2  128
#define W2  128

using short8  = __attribute__((ext_vector_type(8))) short;
using floatx4 = __attribute__((ext_vector_type(4))) float;

// ---- workspace layout (bytes) ----
#define W1C_OFF 0u                                  // [cls4][tap4][co128][ci256] bf16
#define W1C_N   (4 * 4 * 128 * 256)
#define W2C_OFF (W1C_N * 2)                         // [tap9][o128][ci128] bf16
#define W2C_N   (9 * 128 * 128)
#define KG_OFF  (W2C_OFF + W2C_N * 2)               // [b][h][tap9][w128] fp32
#define KG_N    (B_ * H2 * 9 * W2)
#define Y_OFF   (KG_OFF + KG_N * 4)                 // y bf16 [b][c][h][w]
#define Y_N     (B_ * C2 * H2 * W2)
#define WS_NEEDED ((size_t)Y_OFF + (size_t)Y_N * 2)

static __device__ __forceinline__ unsigned short f2bf(float f) {
    union { float f; unsigned u; } v; v.f = f;
    unsigned r = v.u + 0x7FFFu + ((v.u >> 16) & 1u);   // RNE
    return (unsigned short)(r >> 16);
}
static __device__ __forceinline__ float bf2f(unsigned short h) {
    union { unsigned u; float f; } v; v.u = ((unsigned)h) << 16;
    return v.f;
}

// ---------------------------------------------------------------------------
// Prep: w1 -> w1c[cls=(p*2+pw')][tap=(th*2+tw)][co][ci] bf16, kh=p+2th, kw=pw'+2tw
// ---------------------------------------------------------------------------
__global__ void w1c_kernel(const float* __restrict__ w1, unsigned short* __restrict__ w1c) {
    int i = blockIdx.x * 256 + threadIdx.x;
    const int ci  = i & 255;
    const int co  = (i >> 8) & 127;
    const int tap = (i >> 15) & 3;
    const int cls = i >> 17;
    const int kh  = (cls >> 1) + 2 * (tap >> 1);
    const int kw  = (cls & 1) + 2 * (tap & 1);
    w1c[i] = f2bf(w1[((ci * C2 + co) * 4 + kh) * 4 + kw]);
}

// ---- w2 -> w2c[tap][o][ci] bf16 with flip baked (wk[o,c,i,j] = w2[c,o,2-i,2-j])
__global__ void w2c_kernel(const float* __restrict__ w2, unsigned short* __restrict__ w2c) {
    int i = blockIdx.x * 256 + threadIdx.x;
    const int ci  = i & 127;
    const int o   = (i >> 7) & 127;
    const int tap = i >> 14;
    const int fi  = 2 - tap / 3;
    const int fj  = 2 - tap % 3;
    w2c[i] = f2bf(w2[((ci * C2 + o) * 3 + fi) * 3 + fj]);
}

// ---------------------------------------------------------------------------
// k-kernel: kg[b][h][tap][w] = exp(-0.5 * sum_c (g_pad[c,h+di,w+dj] - g[c,h,w])^2)
// One block per (b,h), 128 threads (one per w).
// ---------------------------------------------------------------------------
__global__ __launch_bounds__(128) void k_kernel(const float* __restrict__ guide,
                                                float* __restrict__ kg) {
    const int h = blockIdx.x;
    const int b = blockIdx.y;
    const int n = threadIdx.x;

    float acc[9];
#pragma unroll
    for (int t = 0; t < 9; ++t) acc[t] = 0.f;

    const float* gb = guide + (size_t)b * C2 * H2 * W2;
    for (int c = 0; c < C2; ++c) {
        const float* gc_row = gb + (c * H2 + h) * W2;
        const float gc = gc_row[n];
#pragma unroll
        for (int di = 0; di < 3; ++di) {
            const int hh = h + di - 1;
            const bool rv = (hh >= 0) && (hh < H2);
            const float* gr = gb + (c * H2 + (rv ? hh : 0)) * W2;
#pragma unroll
            for (int dj = 0; dj < 3; ++dj) {
                const int col = n + dj - 1;
                const bool cv = rv && (col >= 0) && (col < W2);
                const float gn = cv ? gr[col] : 0.f;
                const float d = gn - gc;
                acc[di * 3 + dj] += d * d;
            }
        }
    }
    float* dst = kg + ((b * H2 + h) * 9) * W2 + n;
#pragma unroll
    for (int t = 0; t < 9; ++t) dst[t * W2] = __expf(-0.5f * acc[t]);
}

// ---------------------------------------------------------------------------
// Deconv MFMA: block tile 128co x 128pix (2 same-parity rows x 64 iwA),
// tap loop (4) x ci-chunks (8, BK=32). 16x16x32 bf16 MFMA, wave = 64x64.
// ---------------------------------------------------------------------------
__global__ __launch_bounds__(256, 2) void deconv_mfma(const float* __restrict__ x,
                                                      const unsigned short* __restrict__ w1c,
                                                      const float* __restrict__ b1,
                                                      unsigned short* __restrict__ y) {
    const int pwc = blockIdx.x;                 // 0: even ow, 1: odd ow
    const int pr  = blockIdx.y;                 // 0..63 row-pair
    const int b   = blockIdx.z;
    const int base_oh = (pr >> 1) * 4 + (pr & 1);   // rows base_oh, base_oh+2
    const int p    = (base_oh + 1) & 1;
    const int ihA0 = (base_oh + 1 - p) >> 1;
    const int pwp  = 1 - pwc;                   // kw parity
    const int cls  = p * 2 + pwp;

    const int tid  = threadIdx.x;
    const int lane = tid & 63;
    const int wave = tid >> 6;
    const int wm   = (wave & 1) * 64;
    const int wn   = (wave >> 1) * 64;
    const int quad = lane >> 4;
    const int l15  = lane & 15;

    __shared__ __align__(16) unsigned short As[128 * 40];
    __shared__ __align__(16) unsigned short Bs[128 * 40];

    floatx4 acc[4][4];
#pragma unroll
    for (int mi = 0; mi < 4; ++mi)
#pragma unroll
        for (int ni = 0; ni < 4; ++ni) acc[mi][ni] = (floatx4)0.f;

    for (int tap = 0; tap < 4; ++tap) {
        const int th = tap >> 1, tw = tap & 1;
        const unsigned short* wsrc = w1c + ((cls * 4 + tap) * 128) * 256;
        for (int kc = 0; kc < 8; ++kc) {
            const int ci0 = kc * 32;
            // ---- stage A [co][k] stride 40
#pragma unroll
            for (int s = 0; s < 2; ++s) {
                const int i = s * 256 + tid;            // 0..511
                const int co = i >> 2, q = i & 3;
                const int4 v = *reinterpret_cast<const int4*>(wsrc + co * 256 + ci0 + q * 8);
                *reinterpret_cast<int4*>(As + co * 40 + q * 8) = v;
            }
            // ---- stage B [n][k]: B[n][ci] = x[ci][ihA0+rh-th][n64+pwc-tw]
#pragma unroll
            for (int it = 0; it < 8; ++it) {
                const int cb = it * 4 + (tid >> 6);     // 0..31
                const int kp = cb >> 1, rh = cb & 1;
                const int n64 = tid & 63;
                const int ci = ci0 + kp * 2;
                const int ih = ihA0 + rh - th;
                const int iw = n64 + pwc - tw;
                const bool v = (ih >= 0) && (ih < HH) && (iw >= 0) && (iw < WW);
                const float* xp = x + (((size_t)b * C1 + ci) * HH + (v ? ih : 0)) * WW + (v ? iw : 0);
                const float v0 = v ? xp[0] : 0.f;
                const float v1 = v ? xp[HH * WW] : 0.f;
                const unsigned pk = (unsigned)f2bf(v0) | ((unsigned)f2bf(v1) << 16);
                *reinterpret_cast<unsigned*>(Bs + (rh * 64 + n64) * 40 + kp * 2) = pk;
            }
            __syncthreads();

            short8 af[4], bfr[4];
#pragma unroll
            for (int mi = 0; mi < 4; ++mi)
                af[mi] = *reinterpret_cast<const short8*>(As + (wm + mi * 16 + l15) * 40 + quad * 8);
#pragma unroll
            for (int ni = 0; ni < 4; ++ni)
                bfr[ni] = *reinterpret_cast<const short8*>(Bs + (wn + ni * 16 + l15) * 40 + quad * 8);
#pragma unroll
            for (int mi = 0; mi < 4; ++mi)
#pragma unroll
                for (int ni = 0; ni < 4; ++ni)
                    acc[mi][ni] = __builtin_amdgcn_mfma_f32_16x16x32_bf16(af[mi], bfr[ni], acc[mi][ni], 0, 0, 0);
            __syncthreads();
        }
    }

    // ---- epilogue: y bf16, rows {base_oh, base_oh+2}, ow = 2*n64 + pwc
#pragma unroll
    for (int mi = 0; mi < 4; ++mi) {
#pragma unroll
        for (int ni = 0; ni < 4; ++ni) {
            const int n   = wn + ni * 16 + l15;
            const int rh  = n >> 6;
            const int n64 = n & 63;
            const int oh  = base_oh + 2 * rh;
            const int ow  = 2 * n64 + pwc;
#pragma unroll
            for (int r = 0; r < 4; ++r) {
                const int co = wm + mi * 16 + quad * 4 + r;
                const float val = acc[mi][ni][r] + b1[co];
                y[(((size_t)b * C2 + co) * H2 + oh) * W2 + ow] = f2bf(val);
            }
        }
    }
}

// ---------------------------------------------------------------------------
// PAC MFMA: block tile 128o x 128w for fixed (b,h); tap loop (9) x ci-chunks
// (4, BK=32). B staged as bf16(y[ci][h+di][w+dj] * k_tap[w]).
// ---------------------------------------------------------------------------
__global__ __launch_bounds__(256, 2) void pac_mfma(const unsigned short* __restrict__ y,
                                                   const float* __restrict__ kg,
                                                   const unsigned short* __restrict__ w2c,
                                                   const float* __restrict__ b2,
                                                   float* __restrict__ out) {
    const int h = blockIdx.x;
    const int b = blockIdx.y;

    const int tid  = threadIdx.x;
    const int lane = tid & 63;
    const int wave = tid >> 6;
    const int wm   = (wave & 1) * 64;
    const int wn   = (wave >> 1) * 64;
    const int quad = lane >> 4;
    const int l15  = lane & 15;

    __shared__ __align__(16) unsigned short As[128 * 40];
    __shared__ __align__(16) unsigned short Bs[128 * 40];
    __shared__ float k_lds[9 * 128];

    for (int i = tid; i < 9 * 128; i += 256)
        k_lds[i] = kg[(size_t)(b * H2 + h) * 9 * W2 + i];

    floatx4 acc[4][4];
#pragma unroll
    for (int mi = 0; mi < 4; ++mi)
#pragma unroll
        for (int ni = 0; ni < 4; ++ni) acc[mi][ni] = (floatx4)0.f;
    __syncthreads();

    for (int tap = 0; tap < 9; ++tap) {
        const int di = tap / 3 - 1;
        const int dj = tap % 3 - 1;
        const int hh = h + di;
        if (hh < 0 || hh >= H2) continue;          // block-uniform
        const unsigned short* wsrc = w2c + tap * 128 * 128;
        for (int kc = 0; kc < 4; ++kc) {
            const int ci0 = kc * 32;
#pragma unroll
            for (int s = 0; s < 2; ++s) {
                const int i = s * 256 + tid;
                const int o = i >> 2, q = i & 3;
                const int4 v = *reinterpret_cast<const int4*>(wsrc + o * 128 + ci0 + q * 8);
                *reinterpret_cast<int4*>(As + o * 40 + q * 8) = v;
            }
#pragma unroll
            for (int it = 0; it < 8; ++it) {
                const int cb = it * 4 + (tid >> 6);    // 0..31
                const int kp = cb >> 1, nh = cb & 1;
                const int n  = nh * 64 + (tid & 63);
                const int ci = ci0 + kp * 2;
                const int col = n + dj;
                const bool v = (col >= 0) && (col < W2);
                const unsigned short* yp = y + (((size_t)b * C2 + ci) * H2 + hh) * W2 + (v ? col : 0);
                const float kv = k_lds[tap * 128 + n];
                const float v0 = v ? bf2f(yp[0]) * kv : 0.f;
                const float v1 = v ? bf2f(yp[H2 * W2]) * kv : 0.f;
                const unsigned pk = (unsigned)f2bf(v0) | ((unsigned)f2bf(v1) << 16);
                *reinterpret_cast<unsigned*>(Bs + n * 40 + kp * 2) = pk;
            }
            __syncthreads();

            short8 af[4], bfr[4];
#pragma unroll
            for (int mi = 0; mi < 4; ++mi)
                af[mi] = *reinterpret_cast<const short8*>(As + (wm + mi * 16 + l15) * 40 + quad * 8);
#pragma unroll
            for (int ni = 0; ni < 4; ++ni)
                bfr[ni] = *reinterpret_cast<const short8*>(Bs + (wn + ni * 16 + l15) * 40 + quad * 8);
#pragma unroll
            for (int mi = 0; mi < 4; ++mi)
#pragma unroll
                for (int ni = 0; ni < 4; ++ni)
                    acc[mi][ni] = __builtin_amdgcn_mfma_f32_16x16x32_bf16(af[mi], bfr[ni], acc[mi][ni], 0, 0, 0);
            __syncthreads();
        }
    }

#pragma unroll
    for (int mi = 0; mi < 4; ++mi) {
#pragma unroll
        for (int ni = 0; ni < 4; ++ni) {
            const int w = wn + ni * 16 + l15;
#pragma unroll
            for (int r = 0; r < 4; ++r) {
                const int o = wm + mi * 16 + quad * 4 + r;
                out[(((size_t)b * C2 + o) * H2 + h) * W2 + w] = acc[mi][ni][r] + b2[o];
            }
        }
    }
}

extern "C" void kernel_launch(void* const* d_in, const int* in_sizes, int n_in,
                              void* d_out, int out_size, void* d_ws, size_t ws_size,
                              hipStream_t stream) {
    const float* x     = (const float*)d_in[0];
    const float* guide = (const float*)d_in[1];
    const float* w1    = (const float*)d_in[2];
    const float* b1    = (const float*)d_in[3];
    const float* w2    = (const float*)d_in[4];
    const float* b2    = (const float*)d_in[5];
    float* out = (float*)d_out;

    unsigned short* w1c = (unsigned short*)((char*)d_ws + W1C_OFF);
    unsigned short* w2c = (unsigned short*)((char*)d_ws + W2C_OFF);
    float*          kg  = (float*)((char*)d_ws + KG_OFF);
    unsigned short* y   = (unsigned short*)((char*)d_ws + Y_OFF);

    w1c_kernel<<<W1C_N / 256, 256, 0, stream>>>(w1, w1c);
    w2c_kernel<<<W2C_N / 256, 256, 0, stream>>>(w2, w2c);
    k_kernel<<<dim3(H2, B_), 128, 0, stream>>>(guide, kg);
    deconv_mfma<<<dim3(2, 64, B_), 256, 0, stream>>>(x, w1c, b1, y);
    pac_mfma<<<dim3(H2, B_), 256, 0, stream>>>(y, kg, w2c, b2, out);
}

// Round 4
// 209.814 us; speedup vs baseline: 8.5430x; 1.9989x over previous
//
#include <hip/hip_runtime.h>

#define B_  4
#define C1  256
#define C2  128
#define HH  64
#define WW  64
#define H2  128
#define W2  128

using short8  = __attribute__((ext_vector_type(8))) short;
using floatx4 = __attribute__((ext_vector_type(4))) float;
typedef unsigned short ushort_t;

// ---- workspace layout (bytes) ----
#define W1C_OFF 0u                                   // [cls4][tap4][co128][ci256] bf16
#define W1C_ELEMS (4 * 4 * 128 * 256)
#define W2C_OFF (W1C_ELEMS * 2u)                     // [tap9][o128][ci128] bf16
#define W2C_ELEMS (9 * 128 * 128)
#define KG_OFF  (W2C_OFF + W2C_ELEMS * 2u)           // [b][h][tap9][w128] fp32
#define KG_ELEMS (B_ * H2 * 9 * W2)
#define XT_OFF  (KG_OFF + KG_ELEMS * 4u)             // x -> [b][ih][iw][ci] bf16
#define XT_ELEMS (B_ * HH * WW * C1)
#define Y_OFF   (XT_OFF + XT_ELEMS * 2u)             // y -> [b][h][w][c] bf16
#define Y_ELEMS (B_ * H2 * W2 * C2)

static __device__ __forceinline__ ushort_t f2bf(float f) {
    union { float f; unsigned u; } v; v.f = f;
    unsigned r = v.u + 0x7FFFu + ((v.u >> 16) & 1u);   // RNE
    return (ushort_t)(r >> 16);
}

// ---------------------------------------------------------------------------
// Prep: w1 -> w1c[cls][tap][co][ci] bf16 (cls=p*2+pw', tap=th*2+tw)
// ---------------------------------------------------------------------------
__global__ void w1c_kernel(const float* __restrict__ w1, ushort_t* __restrict__ w1c) {
    int i = blockIdx.x * 256 + threadIdx.x;
    const int ci  = i & 255;
    const int co  = (i >> 8) & 127;
    const int tap = (i >> 15) & 3;
    const int cls = i >> 17;
    const int kh  = (cls >> 1) + 2 * (tap >> 1);
    const int kw  = (cls & 1) + 2 * (tap & 1);
    w1c[i] = f2bf(w1[((ci * C2 + co) * 4 + kh) * 4 + kw]);
}

// w2 -> w2c[tap][o][ci] bf16 with flip baked in
__global__ void w2c_kernel(const float* __restrict__ w2, ushort_t* __restrict__ w2c) {
    int i = blockIdx.x * 256 + threadIdx.x;
    const int ci  = i & 127;
    const int o   = (i >> 7) & 127;
    const int tap = i >> 14;
    const int fi  = 2 - tap / 3;
    const int fj  = 2 - tap % 3;
    w2c[i] = f2bf(w2[((ci * C2 + o) * 3 + fi) * 3 + fj]);
}

// x (NCHW fp32) -> xT[b][ih][iw][ci] bf16 via LDS transpose
__global__ __launch_bounds__(256) void xt_kernel(const float* __restrict__ x,
                                                 ushort_t* __restrict__ xT) {
    const int ih = blockIdx.x;
    const int b  = blockIdx.y;
    const int tid = threadIdx.x;
    __shared__ ushort_t tile[64 * 72];    // [iw][cc], stride 72 (16B-aligned rows)

    for (int chunk = 0; chunk < 4; ++chunk) {
        const int ci0 = chunk * 64;
        if (chunk) __syncthreads();
#pragma unroll
        for (int it = 0; it < 16; ++it) {
            const int cc = it * 4 + (tid >> 6);
            const int iw = tid & 63;
            const float v = x[(((size_t)b * C1 + ci0 + cc) * HH + ih) * WW + iw];
            tile[iw * 72 + cc] = f2bf(v);
        }
        __syncthreads();
#pragma unroll
        for (int it = 0; it < 2; ++it) {
            const int i  = it * 256 + tid;
            const int iw = i >> 3;
            const int t  = i & 7;
            const int4 v = *reinterpret_cast<const int4*>(&tile[iw * 72 + t * 8]);
            *reinterpret_cast<int4*>(&xT[(((size_t)(b * HH + ih) * WW) + iw) * C1 + ci0 + t * 8]) = v;
        }
    }
}

// ---------------------------------------------------------------------------
// k-kernel: kg[b][h][tap][w], 512 threads = 4 c-quarters x 128 w, LDS-reduced.
// ---------------------------------------------------------------------------
__global__ __launch_bounds__(512) void k_kernel(const float* __restrict__ guide,
                                                float* __restrict__ kg) {
    const int h = blockIdx.x;
    const int b = blockIdx.y;
    const int tid = threadIdx.x;
    const int cq  = tid >> 7;
    const int n   = tid & 127;

    float acc[9];
#pragma unroll
    for (int t = 0; t < 9; ++t) acc[t] = 0.f;

    const float* gb = guide + (size_t)b * C2 * H2 * W2;
    for (int c = cq * 32; c < cq * 32 + 32; ++c) {
        const float* grow = gb + (c * H2 + h) * W2;
        const float gc = grow[n];
#pragma unroll
        for (int di = 0; di < 3; ++di) {
            const int hh = h + di - 1;
            const bool rv = (hh >= 0) && (hh < H2);
            const float* gr = gb + (c * H2 + (rv ? hh : 0)) * W2;
#pragma unroll
            for (int dj = 0; dj < 3; ++dj) {
                const int col = n + dj - 1;
                const bool cv = rv && (col >= 0) && (col < W2);
                const float gn = cv ? gr[col] : 0.f;
                const float d = gn - gc;
                acc[di * 3 + dj] += d * d;
            }
        }
    }

    __shared__ float part[4][9][128];
#pragma unroll
    for (int t = 0; t < 9; ++t) part[cq][t][n] = acc[t];
    __syncthreads();

    for (int i = tid; i < 1152; i += 512) {
        const int t  = i >> 7;
        const int nn = i & 127;
        const float s = part[0][t][nn] + part[1][t][nn] + part[2][t][nn] + part[3][t][nn];
        kg[(size_t)(b * H2 + h) * 1152 + i] = __expf(-0.5f * s);
    }
}

// ---------------------------------------------------------------------------
// Deconv MFMA v2: tile 128co x 128pix, K=256 in 4 chunks of 64, 4 taps.
// A = w1c rows (contig ci), B = xT rows (contig ci). Epilogue: LDS transpose
// -> y channel-last bf16.
// ---------------------------------------------------------------------------
__global__ __launch_bounds__(256, 2) void deconv_mfma(const ushort_t* __restrict__ xT,
                                                      const ushort_t* __restrict__ w1c,
                                                      const float* __restrict__ b1,
                                                      ushort_t* __restrict__ y) {
    const int pwc = blockIdx.x;
    const int pr  = blockIdx.y;
    const int b   = blockIdx.z;
    const int base_oh = (pr >> 1) * 4 + (pr & 1);
    const int p    = (base_oh + 1) & 1;
    const int ihA0 = (base_oh + 1 - p) >> 1;
    const int pwp  = 1 - pwc;
    const int cls  = p * 2 + pwp;

    const int tid  = threadIdx.x;
    const int lane = tid & 63;
    const int wave = tid >> 6;
    const int wm   = (wave & 1) * 64;
    const int wn   = (wave >> 1) * 64;
    const int quad = lane >> 4;
    const int l15  = lane & 15;

    __shared__ __align__(16) ushort_t lds[2 * 128 * 72];   // As | Bs, stride 72
    ushort_t* As = lds;
    ushort_t* Bs = lds + 128 * 72;

    floatx4 acc[4][4];
#pragma unroll
    for (int mi = 0; mi < 4; ++mi)
#pragma unroll
        for (int ni = 0; ni < 4; ++ni) acc[mi][ni] = (floatx4)0.f;

    for (int kc = 0; kc < 4; ++kc) {
        const int ci0 = kc * 64;
        for (int tap = 0; tap < 4; ++tap) {
            const int th = tap >> 1, tw = tap & 1;
            __syncthreads();
            // ---- stage A: 128 rows x 64 ci = 1024 int4
#pragma unroll
            for (int it = 0; it < 4; ++it) {
                const int i   = it * 256 + tid;
                const int row = i >> 3;
                const int t   = i & 7;
                const int4 v = *reinterpret_cast<const int4*>(
                    &w1c[((size_t)(cls * 4 + tap) * 128 + row) * 256 + ci0 + t * 8]);
                *reinterpret_cast<int4*>(&As[row * 72 + t * 8]) = v;
            }
            // ---- stage B: 128 rows x 64 ci from xT (zero OOB rows)
#pragma unroll
            for (int it = 0; it < 4; ++it) {
                const int i   = it * 256 + tid;
                const int row = i >> 3;
                const int t   = i & 7;
                const int rh  = row >> 6;
                const int n64 = row & 63;
                const int ih  = ihA0 + rh - th;
                const int iw  = n64 + pwc - tw;
                int4 v = make_int4(0, 0, 0, 0);
                if (ih >= 0 && ih < HH && iw >= 0 && iw < WW)
                    v = *reinterpret_cast<const int4*>(
                        &xT[(((size_t)(b * HH + ih) * WW) + iw) * C1 + ci0 + t * 8]);
                *reinterpret_cast<int4*>(&Bs[row * 72 + t * 8]) = v;
            }
            __syncthreads();
#pragma unroll
            for (int k2 = 0; k2 < 2; ++k2) {
                short8 af[4], bfr[4];
#pragma unroll
                for (int mi = 0; mi < 4; ++mi)
                    af[mi] = *reinterpret_cast<const short8*>(
                        &As[(wm + mi * 16 + l15) * 72 + k2 * 32 + quad * 8]);
#pragma unroll
                for (int ni = 0; ni < 4; ++ni)
                    bfr[ni] = *reinterpret_cast<const short8*>(
                        &Bs[(wn + ni * 16 + l15) * 72 + k2 * 32 + quad * 8]);
#pragma unroll
                for (int mi = 0; mi < 4; ++mi)
#pragma unroll
                    for (int ni = 0; ni < 4; ++ni)
                        acc[mi][ni] = __builtin_amdgcn_mfma_f32_16x16x32_bf16(
                            af[mi], bfr[ni], acc[mi][ni], 0, 0, 0);
            }
        }
    }

    // ---- epilogue: transpose in LDS -> y[b][oh][ow][co] bf16
    __syncthreads();
    ushort_t* Ot = lds;                      // [n 0..127][co 0..127], stride 136
#pragma unroll
    for (int mi = 0; mi < 4; ++mi)
#pragma unroll
        for (int ni = 0; ni < 4; ++ni) {
            const int n = wn + ni * 16 + l15;
#pragma unroll
            for (int r = 0; r < 4; ++r) {
                const int co = wm + mi * 16 + quad * 4 + r;
                Ot[n * 136 + co] = f2bf(acc[mi][ni][r] + b1[co]);
            }
        }
    __syncthreads();
#pragma unroll
    for (int it = 0; it < 8; ++it) {
        const int i   = it * 256 + tid;
        const int n   = i >> 4;
        const int t   = i & 15;
        const int rh  = n >> 6;
        const int n64 = n & 63;
        const int oh  = base_oh + 2 * rh;
        const int ow  = 2 * n64 + pwc;
        const int4 v = *reinterpret_cast<const int4*>(&Ot[n * 136 + t * 8]);
        *reinterpret_cast<int4*>(&y[(((size_t)(b * H2 + oh) * W2) + ow) * C2 + t * 8]) = v;
    }
}

// ---------------------------------------------------------------------------
// PAC MFMA v2: tile 128o x 128w per (b,h). Y-slab staged once per tap-row di
// (reused by 3 taps); per-tap GEMM over K=128, scaled by k in register epilogue.
// ---------------------------------------------------------------------------
__global__ __launch_bounds__(256, 2) void pac_mfma(const ushort_t* __restrict__ y,
                                                   const float* __restrict__ kg,
                                                   const ushort_t* __restrict__ w2c,
                                                   const float* __restrict__ b2,
                                                   float* __restrict__ out) {
    const int h = blockIdx.x;
    const int b = blockIdx.y;

    const int tid  = threadIdx.x;
    const int lane = tid & 63;
    const int wave = tid >> 6;
    const int wm   = (wave & 1) * 64;
    const int wn   = (wave >> 1) * 64;
    const int quad = lane >> 4;
    const int l15  = lane & 15;

    __shared__ __align__(16) ushort_t As[128 * 136];   // weights per tap
    __shared__ __align__(16) ushort_t Ys[130 * 136];   // y slab per di (rows = col+1)
    __shared__ float k_lds[9 * 128];

    for (int i = tid; i < 1152; i += 256)
        k_lds[i] = kg[(size_t)(b * H2 + h) * 1152 + i];

    float out_acc[4][4][4];
#pragma unroll
    for (int mi = 0; mi < 4; ++mi)
#pragma unroll
        for (int ni = 0; ni < 4; ++ni)
#pragma unroll
            for (int r = 0; r < 4; ++r) out_acc[mi][ni][r] = 0.f;

    for (int di = 0; di < 3; ++di) {
        const int hh = h + di - 1;
        if (hh < 0 || hh >= H2) continue;              // block-uniform
        __syncthreads();                               // prior tap's Ys readers done
        // ---- stage Y slab: cols -1..128 -> rows 0..129 (128 interior + 2 zero)
#pragma unroll
        for (int it = 0; it < 8; ++it) {
            const int i  = it * 256 + tid;
            const int r  = i >> 4;
            const int t  = i & 15;
            const int4 v = *reinterpret_cast<const int4*>(
                &y[(((size_t)(b * H2 + hh) * W2) + r) * C2 + t * 8]);
            *reinterpret_cast<int4*>(&Ys[(r + 1) * 136 + t * 8]) = v;
        }
        if (tid < 32) {
            const int ra = (tid < 16) ? 0 : 129;
            const int t  = tid & 15;
            *reinterpret_cast<int4*>(&Ys[ra * 136 + t * 8]) = make_int4(0, 0, 0, 0);
        }

        for (int dj = 0; dj < 3; ++dj) {
            const int tap = di * 3 + dj;
            __syncthreads();                           // Ys staged / prior As readers done
            // ---- stage A = w2c[tap]: 128 x 128 = 2048 int4
#pragma unroll
            for (int it = 0; it < 8; ++it) {
                const int i   = it * 256 + tid;
                const int row = i >> 4;
                const int t   = i & 15;
                const int4 v = *reinterpret_cast<const int4*>(
                    &w2c[((size_t)tap * 128 + row) * 128 + t * 8]);
                *reinterpret_cast<int4*>(&As[row * 136 + t * 8]) = v;
            }
            __syncthreads();

            floatx4 acc[4][4];
#pragma unroll
            for (int mi = 0; mi < 4; ++mi)
#pragma unroll
                for (int ni = 0; ni < 4; ++ni) acc[mi][ni] = (floatx4)0.f;

#pragma unroll
            for (int kc = 0; kc < 4; ++kc) {
                short8 af[4], bfr[4];
#pragma unroll
                for (int mi = 0; mi < 4; ++mi)
                    af[mi] = *reinterpret_cast<const short8*>(
                        &As[(wm + mi * 16 + l15) * 136 + kc * 32 + quad * 8]);
#pragma unroll
                for (int ni = 0; ni < 4; ++ni)
                    bfr[ni] = *reinterpret_cast<const short8*>(
                        &Ys[(wn + ni * 16 + l15 + dj) * 136 + kc * 32 + quad * 8]);
#pragma unroll
                for (int mi = 0; mi < 4; ++mi)
#pragma unroll
                    for (int ni = 0; ni < 4; ++ni)
                        acc[mi][ni] = __builtin_amdgcn_mfma_f32_16x16x32_bf16(
                            af[mi], bfr[ni], acc[mi][ni], 0, 0, 0);
            }
            // ---- scale by k_tap[w] and accumulate
            float kv[4];
#pragma unroll
            for (int ni = 0; ni < 4; ++ni)
                kv[ni] = k_lds[tap * 128 + wn + ni * 16 + l15];
#pragma unroll
            for (int mi = 0; mi < 4; ++mi)
#pragma unroll
                for (int ni = 0; ni < 4; ++ni)
#pragma unroll
                    for (int r = 0; r < 4; ++r)
                        out_acc[mi][ni][r] += kv[ni] * acc[mi][ni][r];
        }
    }

    // ---- final store: out NCHW fp32
#pragma unroll
    for (int mi = 0; mi < 4; ++mi)
#pragma unroll
        for (int ni = 0; ni < 4; ++ni) {
            const int w = wn + ni * 16 + l15;
#pragma unroll
            for (int r = 0; r < 4; ++r) {
                const int o = wm + mi * 16 + quad * 4 + r;
                out[(((size_t)b * C2 + o) * H2 + h) * W2 + w] = out_acc[mi][ni][r] + b2[o];
            }
        }
}

extern "C" void kernel_launch(void* const* d_in, const int* in_sizes, int n_in,
                              void* d_out, int out_size, void* d_ws, size_t ws_size,
                              hipStream_t stream) {
    const float* x     = (const float*)d_in[0];
    const float* guide = (const float*)d_in[1];
    const float* w1    = (const float*)d_in[2];
    const float* b1    = (const float*)d_in[3];
    const float* w2    = (const float*)d_in[4];
    const float* b2    = (const float*)d_in[5];
    float* out = (float*)d_out;

    ushort_t* w1c = (ushort_t*)((char*)d_ws + W1C_OFF);
    ushort_t* w2c = (ushort_t*)((char*)d_ws + W2C_OFF);
    float*    kg  = (float*)((char*)d_ws + KG_OFF);
    ushort_t* xT  = (ushort_t*)((char*)d_ws + XT_OFF);
    ushort_t* y   = (ushort_t*)((char*)d_ws + Y_OFF);

    w1c_kernel<<<W1C_ELEMS / 256, 256, 0, stream>>>(w1, w1c);
    w2c_kernel<<<W2C_ELEMS / 256, 256, 0, stream>>>(w2, w2c);
    xt_kernel<<<dim3(HH, B_), 256, 0, stream>>>(x, xT);
    k_kernel<<<dim3(H2, B_), 512, 0, stream>>>(guide, kg);
    deconv_mfma<<<dim3(2, 64, B_), 256, 0, stream>>>(xT, w1c, b1, y);
    pac_mfma<<<dim3(H2, B_), 256, 0, stream>>>(y, kg, w2c, b2, out);
}